// Round 18
// baseline (171.335 us; speedup 1.0000x reference)
//
#include <hip/hip_runtime.h>

#define ED 64
#define HD 4
#define BD 1024
#define SNEG 22222
#define NT2 1408             // 8 col-groups x 176 tiles (4 waves x 44)
#define SPAD2 22528
#define SP1 (SNEG+1)         // 22223
#define LOGQ -3.81776242f
#define LOG2E 1.44269504f

typedef short bf16x8 __attribute__((ext_vector_type(8)));
typedef float f32x4 __attribute__((ext_vector_type(4)));

static __device__ __forceinline__ short f2bf(float f) {
    union { float f; unsigned u; } v; v.f = f;
    return (short)((v.u + 0x7FFFu + ((v.u >> 16) & 1u)) >> 16);
}

static __device__ __forceinline__ float fast_tanh(float x) {
    float ax = __builtin_fabsf(x);
    float e  = __expf(-2.f * ax);
    float t  = (1.f - e) / (1.f + e);
    return __builtin_copysignf(t, x);
}

static __device__ __forceinline__ float fexp2(float x) {
#if __has_builtin(__builtin_amdgcn_exp2f)
    return __builtin_amdgcn_exp2f(x);
#else
    return __expf(x * 0.69314718f);
#endif
}

// ---------------- kernel 1: fused setup, 256 blocks ------------------------
__global__ __launch_bounds__(256) void k_setup(
        const float* __restrict__ inputs, const float* __restrict__ emb,
        const float* __restrict__ proj,   const float* __restrict__ mix,
        const float* __restrict__ biases, const int* __restrict__ label,
        const int* __restrict__ sids,
        short* __restrict__ A, float* __restrict__ pi, float* __restrict__ tl,
        short* __restrict__ W, float* __restrict__ bias_s,
        float* __restrict__ denom, int* __restrict__ cnt, int* __restrict__ gcnt) {
    const int blk = blockIdx.x, t = threadIdx.x;
    __shared__ float s_in[64];
    __shared__ float s_proj[256];
    __shared__ float s_mix[4];
    __shared__ float s_red[256];

    if (t < 16) denom[blk*16 + t] = 0.f;
    if (blk == 0) {
        if (t < 64) cnt[t] = 0;
        if (t == 64) gcnt[0] = 0;
    }

    #pragma unroll 1
    for (int bi = 0; bi < 4; ++bi) {
        int b = blk*4 + bi;
        if (t < 64) s_in[t] = inputs[b*64 + t];
        __syncthreads();
        const float* pr = proj + t*64;
        float dot = 0.f;
        #pragma unroll
        for (int k = 0; k < 64; k += 4)
            dot += s_in[k]*pr[k] + s_in[k+1]*pr[k+1] + s_in[k+2]*pr[k+2] + s_in[k+3]*pr[k+3];
        float val = fast_tanh(dot);
        s_proj[t] = val;
        A[(b*4 + (t >> 6))*64 + (t & 63)] = f2bf(val * LOG2E);   // pre-scaled
        if (t < 4) {
            const float* mr = mix + t*64;
            float md = 0.f;
            for (int k = 0; k < 64; ++k) md += s_in[k]*mr[k];
            s_mix[t] = md;
        }
        int lab = label[b];
        s_red[t] = s_proj[t] * emb[(size_t)lab*64 + (t & 63)];
        __syncthreads();
        if (t < 4) {
            float m = fmaxf(fmaxf(s_mix[0], s_mix[1]), fmaxf(s_mix[2], s_mix[3]));
            float e0 = __expf(s_mix[0]-m), e1 = __expf(s_mix[1]-m);
            float e2 = __expf(s_mix[2]-m), e3 = __expf(s_mix[3]-m);
            pi[b*4 + t] = __expf(s_mix[t]-m) / (e0+e1+e2+e3);
            float sum = 0.f;
            for (int k = 0; k < 64; ++k) sum += s_red[t*64 + k];
            tl[b*4 + t] = (sum + biases[lab] - LOGQ) * LOG2E;    // base-2
        }
        __syncthreads();
    }

    #pragma unroll 1
    for (int rep = 0; rep < 3; ++rep) {
        int task = rep*256 + t;
        if (task >= 704) break;
        int s = blk*88 + (task >> 3);
        int l8 = task & 7;
        if (s < SNEG) {
            int id = sids[s];
            const float* src = emb + (size_t)id*64 + l8*8;
            bf16x8 o;
            #pragma unroll
            for (int j = 0; j < 8; ++j) o[j] = f2bf(src[j]);
            *(bf16x8*)(W + s*64 + l8*8) = o;
            if (l8 == 0) bias_s[s] = (biases[id] - LOGQ) * LOG2E;
        } else {
            bf16x8 o;
            #pragma unroll
            for (int j = 0; j < 8; ++j) o[j] = 0;
            *(bf16x8*)(W + s*64 + l8*8) = o;
            if (l8 == 0) bias_s[s] = -1e30f;
        }
    }
}

#define LOADT(S, T) { \
    const bf16x8* bp_ = (const bf16x8*)(W + (size_t)((T)*16 + c)*64); \
    b0##S = bp_[g]; b1##S = bp_[4 + g]; bb##S = bias_s[(T)*16 + c]; }

#define DCOMP(S) { \
    _Pragma("unroll") \
    for (int t4 = 0; t4 < 4; ++t4) { \
        f32x4 z = {bb##S, bb##S, bb##S, bb##S}; \
        z = __builtin_amdgcn_mfma_f32_16x16x32_bf16(a0[t4], b0##S, z, 0, 0, 0); \
        z = __builtin_amdgcn_mfma_f32_16x16x32_bf16(a1[t4], b1##S, z, 0, 0, 0); \
        s[t4*4+0] += fexp2(z[0]); \
        s[t4*4+1] += fexp2(z[1]); \
        s[t4*4+2] += fexp2(z[2]); \
        s[t4*4+3] += fexp2(z[3]); } }

#define PCOMP(S, T) { \
    int scol_ = (T)*16 + c; bool ok_ = scol_ < SNEG; \
    _Pragma("unroll") \
    for (int t4 = 0; t4 < 4; ++t4) { \
        f32x4 z = {bb##S, bb##S, bb##S, bb##S}; \
        z = __builtin_amdgcn_mfma_f32_16x16x32_bf16(a0[t4], b0##S, z, 0, 0, 0); \
        z = __builtin_amdgcn_mfma_f32_16x16x32_bf16(a1[t4], b1##S, z, 0, 0, 0); \
        float p_ = cf[t4][0]*fexp2(z[0]); \
        p_ = fmaf(cf[t4][1], fexp2(z[1]), p_); \
        p_ = fmaf(cf[t4][2], fexp2(z[2]), p_); \
        p_ = fmaf(cf[t4][3], fexp2(z[3]), p_); \
        if (ok_) orow[t4][scol_] = p_; } }

#define DPIPE(TB) { \
    LOADT(A, (TB)+0) LOADT(B, (TB)+1) LOADT(C, (TB)+2) \
    DCOMP(A) LOADT(A, (TB)+3) \
    DCOMP(B) LOADT(B, (TB)+4) \
    DCOMP(C) LOADT(C, (TB)+5) \
    DCOMP(A) LOADT(A, (TB)+6) \
    DCOMP(B) LOADT(B, (TB)+7) \
    DCOMP(C) LOADT(C, (TB)+8) \
    DCOMP(A) LOADT(A, (TB)+9) \
    DCOMP(B) LOADT(B, (TB)+10) \
    DCOMP(C) \
    DCOMP(A) \
    DCOMP(B) }

#define PPIPE(TB) { \
    LOADT(A, (TB)+0) LOADT(B, (TB)+1) LOADT(C, (TB)+2) \
    PCOMP(A, (TB)+0)  LOADT(A, (TB)+3) \
    PCOMP(B, (TB)+1)  LOADT(B, (TB)+4) \
    PCOMP(C, (TB)+2)  LOADT(C, (TB)+5) \
    PCOMP(A, (TB)+3)  LOADT(A, (TB)+6) \
    PCOMP(B, (TB)+4)  LOADT(B, (TB)+7) \
    PCOMP(C, (TB)+5)  LOADT(C, (TB)+8) \
    PCOMP(A, (TB)+6)  LOADT(A, (TB)+9) \
    PCOMP(B, (TB)+7)  LOADT(B, (TB)+10) \
    PCOMP(C, (TB)+8) \
    PCOMP(A, (TB)+9) \
    PCOMP(B, (TB)+10) }

// -------- kernel 2: FUSED denom + probs, grid (8,64) = 512 blocks ----------
// Phase 1: denom partials + atomicAdd. Then 8-way completion barrier per
// row-group (cnt[by]): the only producers of denom rows [64*by,64*by+64) are
// the 8 blocks sharing by, all guaranteed co-resident (512 blocks <= capacity
// at launch_bounds(256,4)). Phase 2: probs using the same A-frags (still in
// registers) and L2-hot W.
__global__ __launch_bounds__(256, 4) void k_fused(
        const short* __restrict__ A, const short* __restrict__ W,
        const float* __restrict__ bias_s, const float* __restrict__ pi,
        const float* __restrict__ tl, float* __restrict__ denom,
        int* __restrict__ cnt, int* __restrict__ gcnt,
        float* __restrict__ out) {
    const int t = threadIdx.x;
    const int wave = t >> 6, lane = t & 63;
    const int g = lane >> 4, c = lane & 15;
    const int bx = blockIdx.x, by = blockIdx.y;
    const int rbase = by * 64;
    const int brow0 = by * 16;
    __shared__ float s_cf[64];
    __shared__ float s_et[64];
    __shared__ float s_ls[4];

    bf16x8 a0[4], a1[4];
    #pragma unroll
    for (int t4 = 0; t4 < 4; ++t4) {
        const bf16x8* ap = (const bf16x8*)(A + (size_t)(rbase + t4*16 + c)*64);
        a0[t4] = ap[g]; a1[t4] = ap[4 + g];
    }

    // ---------------- phase 1: denominators ----------------
    {
        float s[16];
        #pragma unroll
        for (int i = 0; i < 16; ++i) s[i] = 0.f;
        const int t0 = (bx*4 + wave) * 44;
        bf16x8 b0A, b1A, b0B, b1B, b0C, b1C;
        float bbA, bbB, bbC;
        DPIPE(t0)
        DPIPE(t0 + 11)
        DPIPE(t0 + 22)
        DPIPE(t0 + 33)
        #pragma unroll
        for (int m = 1; m < 16; m <<= 1)
            #pragma unroll
            for (int i = 0; i < 16; ++i) s[i] += __shfl_xor(s[i], m);
        if (c == 0) {
            #pragma unroll
            for (int t4 = 0; t4 < 4; ++t4)
                #pragma unroll
                for (int r = 0; r < 4; ++r)
                    atomicAdd(&denom[rbase + t4*16 + g*4 + r], s[t4*4+r]);
        }
    }

    // ---------------- 8-way row-group completion barrier ----------------
    __syncthreads();                 // all waves' atomics drained (vmcnt before barrier)
    if (t == 0) {
        __threadfence();
        atomicAdd(gcnt, 1);          // global completion (for the loss block)
        atomicAdd(&cnt[by], 1);      // row-group completion
        while (__hip_atomic_load(&cnt[by], __ATOMIC_ACQUIRE, __HIP_MEMORY_SCOPE_AGENT) < 8)
            __builtin_amdgcn_s_sleep(1);
    }
    __syncthreads();

    // ---------------- phase 2: coefficients + probs ----------------
    if (t < 64) {
        int row = rbase + t;
        float dv = __hip_atomic_load(&denom[row], __ATOMIC_RELAXED, __HIP_MEMORY_SCOPE_AGENT);
        float et = fexp2(tl[row]);
        float d  = dv + et;
        s_cf[t] = pi[row] / d;
        s_et[t] = et;
    }
    __syncthreads();
    if (bx == 0 && t < 16) {
        float p0 = 0.f;
        #pragma unroll
        for (int h = 0; h < 4; ++h) p0 += s_cf[t*4 + h] * s_et[t*4 + h];
        out[(size_t)(brow0 + t) * SP1] = p0;
    }

    float cf[4][4];
    float* orow[4];
    #pragma unroll
    for (int t4 = 0; t4 < 4; ++t4) {
        #pragma unroll
        for (int r = 0; r < 4; ++r) cf[t4][r] = s_cf[t4*16 + g*4 + r];
        orow[t4] = out + (size_t)(brow0 + t4*4 + g) * SP1 + 1;
    }
    {
        const int t0 = (bx*4 + wave) * 44;
        bf16x8 b0A, b1A, b0B, b1B, b0C, b1C;
        float bbA, bbB, bbC;
        PPIPE(t0)
        PPIPE(t0 + 11)
        PPIPE(t0 + 22)
        PPIPE(t0 + 33)
    }

    // ---------------- loss (block (0,0) only, at the end) ----------------
    if (bx == 0 && by == 0) {
        if (t == 0) {
            while (__hip_atomic_load(gcnt, __ATOMIC_ACQUIRE, __HIP_MEMORY_SCOPE_AGENT) < 512)
                __builtin_amdgcn_s_sleep(1);
        }
        __syncthreads();
        float lg = 0.f;
        for (int b = t; b < BD; b += 256) {
            float p0 = 0.f;
            #pragma unroll
            for (int h = 0; h < 4; ++h) {
                float dv = __hip_atomic_load(&denom[b*4 + h], __ATOMIC_RELAXED, __HIP_MEMORY_SCOPE_AGENT);
                float et = fexp2(tl[b*4 + h]);
                p0 += pi[b*4 + h] / (dv + et) * et;
            }
            lg += logf(p0);
        }
        #pragma unroll
        for (int m = 1; m < 64; m <<= 1) lg += __shfl_xor(lg, m);
        if (lane == 0) s_ls[wave] = lg;
        __syncthreads();
        if (t == 0)
            out[(size_t)BD * SP1] = -(s_ls[0]+s_ls[1]+s_ls[2]+s_ls[3]) * (1.f/(float)BD);
    }
}

extern "C" void kernel_launch(void* const* d_in, const int* in_sizes, int n_in,
                              void* d_out, int out_size, void* d_ws, size_t ws_size,
                              hipStream_t stream) {
    const float* inputs = (const float*)d_in[0];
    const float* emb    = (const float*)d_in[1];
    const float* proj   = (const float*)d_in[2];
    const float* mix    = (const float*)d_in[3];
    const float* biases = (const float*)d_in[4];
    const int*   label  = (const int*)d_in[5];
    const int*   sids   = (const int*)d_in[6];
    float* out = (float*)d_out;

    char* ws = (char*)d_ws;
    short* W      = (short*)(ws);                      // 2,883,584 B
    short* A      = (short*)(ws + 2883584);            // 524,288 B
    float* bias_s = (float*)(ws + 3407872);            // 90,112 B
    float* denom  = (float*)(ws + 3497984);            // 16,384 B
    float* pi     = (float*)(ws + 3514368);            // 16,384 B
    float* tl     = (float*)(ws + 3530752);            // 16,384 B
    int*   cnt    = (int*)  (ws + 3547136);            // 256 B
    int*   gcnt   = (int*)  (ws + 3547392);            // 4 B

    k_setup<<<256, 256, 0, stream>>>(
        inputs, emb, proj, mix, biases, label, sids, A, pi, tl, W, bias_s,
        denom, cnt, gcnt);
    k_fused<<<dim3(8, 64), 256, 0, stream>>>(
        A, W, bias_s, pi, tl, denom, cnt, gcnt, out);
}

// Round 19
// 85.501 us; speedup vs baseline: 2.0039x; 2.0039x over previous
//
#include <hip/hip_runtime.h>

#define ED 64
#define HD 4
#define BD 1024
#define SNEG 22222
#define NT2 1408             // 8 col-groups x 176 tiles (4 waves x 44)
#define SPAD2 22528
#define SP1 (SNEG+1)         // 22223
#define LOGQ -3.81776242f
#define LOG2E 1.44269504f

typedef short bf16x8 __attribute__((ext_vector_type(8)));
typedef float f32x4 __attribute__((ext_vector_type(4)));

static __device__ __forceinline__ short f2bf(float f) {
    union { float f; unsigned u; } v; v.f = f;
    return (short)((v.u + 0x7FFFu + ((v.u >> 16) & 1u)) >> 16);
}

static __device__ __forceinline__ float fast_tanh(float x) {
    float ax = __builtin_fabsf(x);
    float e  = __expf(-2.f * ax);
    float t  = (1.f - e) / (1.f + e);
    return __builtin_copysignf(t, x);
}

static __device__ __forceinline__ float fexp2(float x) {
#if __has_builtin(__builtin_amdgcn_exp2f)
    return __builtin_amdgcn_exp2f(x);
#else
    return __expf(x * 0.69314718f);
#endif
}

// ---------------- kernel 1: fused setup, 256 blocks ------------------------
__global__ __launch_bounds__(256) void k_setup(
        const float* __restrict__ inputs, const float* __restrict__ emb,
        const float* __restrict__ proj,   const float* __restrict__ mix,
        const float* __restrict__ biases, const int* __restrict__ label,
        const int* __restrict__ sids,
        short* __restrict__ A, float* __restrict__ pi, float* __restrict__ tl,
        short* __restrict__ W, float* __restrict__ bias_s,
        float* __restrict__ denom) {
    const int blk = blockIdx.x, t = threadIdx.x;
    __shared__ float s_in[64];
    __shared__ float s_proj[256];
    __shared__ float s_mix[4];
    __shared__ float s_red[256];

    if (t < 16) denom[blk*16 + t] = 0.f;

    #pragma unroll 1
    for (int bi = 0; bi < 4; ++bi) {
        int b = blk*4 + bi;
        if (t < 64) s_in[t] = inputs[b*64 + t];
        __syncthreads();
        const float* pr = proj + t*64;
        float dot = 0.f;
        #pragma unroll
        for (int k = 0; k < 64; k += 4)
            dot += s_in[k]*pr[k] + s_in[k+1]*pr[k+1] + s_in[k+2]*pr[k+2] + s_in[k+3]*pr[k+3];
        float val = fast_tanh(dot);
        s_proj[t] = val;
        A[(b*4 + (t >> 6))*64 + (t & 63)] = f2bf(val * LOG2E);   // pre-scaled
        if (t < 4) {
            const float* mr = mix + t*64;
            float md = 0.f;
            for (int k = 0; k < 64; ++k) md += s_in[k]*mr[k];
            s_mix[t] = md;
        }
        int lab = label[b];
        s_red[t] = s_proj[t] * emb[(size_t)lab*64 + (t & 63)];
        __syncthreads();
        if (t < 4) {
            float m = fmaxf(fmaxf(s_mix[0], s_mix[1]), fmaxf(s_mix[2], s_mix[3]));
            float e0 = __expf(s_mix[0]-m), e1 = __expf(s_mix[1]-m);
            float e2 = __expf(s_mix[2]-m), e3 = __expf(s_mix[3]-m);
            pi[b*4 + t] = __expf(s_mix[t]-m) / (e0+e1+e2+e3);
            float sum = 0.f;
            for (int k = 0; k < 64; ++k) sum += s_red[t*64 + k];
            tl[b*4 + t] = (sum + biases[lab] - LOGQ) * LOG2E;    // base-2
        }
        __syncthreads();
    }

    #pragma unroll 1
    for (int rep = 0; rep < 3; ++rep) {
        int task = rep*256 + t;
        if (task >= 704) break;
        int s = blk*88 + (task >> 3);
        int l8 = task & 7;
        if (s < SNEG) {
            int id = sids[s];
            const float* src = emb + (size_t)id*64 + l8*8;
            bf16x8 o;
            #pragma unroll
            for (int j = 0; j < 8; ++j) o[j] = f2bf(src[j]);
            *(bf16x8*)(W + s*64 + l8*8) = o;
            if (l8 == 0) bias_s[s] = (biases[id] - LOGQ) * LOG2E;
        } else {
            bf16x8 o;
            #pragma unroll
            for (int j = 0; j < 8; ++j) o[j] = 0;
            *(bf16x8*)(W + s*64 + l8*8) = o;
            if (l8 == 0) bias_s[s] = -1e30f;
        }
    }
}

#define LOADT(S, T) { \
    const bf16x8* bp_ = (const bf16x8*)(W + (size_t)((T)*16 + c)*64); \
    b0##S = bp_[g]; b1##S = bp_[4 + g]; bb##S = bias_s[(T)*16 + c]; }

#define DCOMP(S) { \
    _Pragma("unroll") \
    for (int t4 = 0; t4 < 4; ++t4) { \
        f32x4 z = {bb##S, bb##S, bb##S, bb##S}; \
        z = __builtin_amdgcn_mfma_f32_16x16x32_bf16(a0[t4], b0##S, z, 0, 0, 0); \
        z = __builtin_amdgcn_mfma_f32_16x16x32_bf16(a1[t4], b1##S, z, 0, 0, 0); \
        s[t4*4+0] += fexp2(z[0]); \
        s[t4*4+1] += fexp2(z[1]); \
        s[t4*4+2] += fexp2(z[2]); \
        s[t4*4+3] += fexp2(z[3]); } }

// probs: mixture-weighted exp -> wave-private LDS tile [16 rows][180] (TL = 0..10)
#define PCOMPL(S, TL) { \
    _Pragma("unroll") \
    for (int t4 = 0; t4 < 4; ++t4) { \
        f32x4 z = {bb##S, bb##S, bb##S, bb##S}; \
        z = __builtin_amdgcn_mfma_f32_16x16x32_bf16(a0[t4], b0##S, z, 0, 0, 0); \
        z = __builtin_amdgcn_mfma_f32_16x16x32_bf16(a1[t4], b1##S, z, 0, 0, 0); \
        float p_ = cf[t4][0]*fexp2(z[0]); \
        p_ = fmaf(cf[t4][1], fexp2(z[1]), p_); \
        p_ = fmaf(cf[t4][2], fexp2(z[2]), p_); \
        p_ = fmaf(cf[t4][3], fexp2(z[3]), p_); \
        swo[(t4*4 + g)*180 + (TL)*16 + c] = p_; } }

#define DPIPE(TB) { \
    LOADT(A, (TB)+0) LOADT(B, (TB)+1) LOADT(C, (TB)+2) \
    DCOMP(A) LOADT(A, (TB)+3) \
    DCOMP(B) LOADT(B, (TB)+4) \
    DCOMP(C) LOADT(C, (TB)+5) \
    DCOMP(A) LOADT(A, (TB)+6) \
    DCOMP(B) LOADT(B, (TB)+7) \
    DCOMP(C) LOADT(C, (TB)+8) \
    DCOMP(A) LOADT(A, (TB)+9) \
    DCOMP(B) LOADT(B, (TB)+10) \
    DCOMP(C) \
    DCOMP(A) \
    DCOMP(B) }

// stage 11 tiles into LDS, then PLAIN-flush 16 rows x 176 contiguous cols
// (A/B vs R17: ONLY the NT store became a cached store)
#define PPIPES(TB) { \
    LOADT(A, (TB)+0) LOADT(B, (TB)+1) LOADT(C, (TB)+2) \
    PCOMPL(A, 0)  LOADT(A, (TB)+3) \
    PCOMPL(B, 1)  LOADT(B, (TB)+4) \
    PCOMPL(C, 2)  LOADT(C, (TB)+5) \
    PCOMPL(A, 3)  LOADT(A, (TB)+6) \
    PCOMPL(B, 4)  LOADT(B, (TB)+7) \
    PCOMPL(C, 5)  LOADT(C, (TB)+8) \
    PCOMPL(A, 6)  LOADT(A, (TB)+9) \
    PCOMPL(B, 7)  LOADT(B, (TB)+10) \
    PCOMPL(C, 8) \
    PCOMPL(A, 9) \
    PCOMPL(B, 10) \
    { int cb_ = (TB)*16; \
      _Pragma("unroll") \
      for (int r_ = 0; r_ < 16; ++r_) { \
        float* drow_ = out + (size_t)(brow0 + r_)*SP1 + 1 + cb_; \
        const float* srow_ = swo + r_*180; \
        _Pragma("unroll") \
        for (int k_ = lane; k_ < 176; k_ += 64) \
            if (cb_ + k_ < SNEG) \
                drow_[k_] = srow_[k_]; } } }

// ---------------- kernel 2: denominators, grid (8,64) ----------------------
__global__ __launch_bounds__(256, 4) void k_denom(
        const short* __restrict__ A, const short* __restrict__ W,
        const float* __restrict__ bias_s, float* __restrict__ denom) {
    const int wave = threadIdx.x >> 6, lane = threadIdx.x & 63;
    const int g = lane >> 4, c = lane & 15;
    const int rbase = blockIdx.y * 64;
    bf16x8 a0[4], a1[4];
    #pragma unroll
    for (int t4 = 0; t4 < 4; ++t4) {
        const bf16x8* ap = (const bf16x8*)(A + (size_t)(rbase + t4*16 + c)*64);
        a0[t4] = ap[g]; a1[t4] = ap[4 + g];
    }
    float s[16];
    #pragma unroll
    for (int i = 0; i < 16; ++i) s[i] = 0.f;

    const int t0 = (blockIdx.x*4 + wave) * 44;
    bf16x8 b0A, b1A, b0B, b1B, b0C, b1C;
    float bbA, bbB, bbC;
    DPIPE(t0)
    DPIPE(t0 + 11)
    DPIPE(t0 + 22)
    DPIPE(t0 + 33)

    #pragma unroll
    for (int m = 1; m < 16; m <<= 1)
        #pragma unroll
        for (int i = 0; i < 16; ++i) s[i] += __shfl_xor(s[i], m);
    if (c == 0) {
        #pragma unroll
        for (int t4 = 0; t4 < 4; ++t4)
            #pragma unroll
            for (int r = 0; r < 4; ++r)
                atomicAdd(&denom[rbase + t4*16 + g*4 + r], s[t4*4+r]);
    }
}

// ---------------- kernel 3: probs (staged PLAIN flush) + out[:,0] + loss ---
__global__ __launch_bounds__(256) void k_probs(
        const short* __restrict__ A, const short* __restrict__ W,
        const float* __restrict__ bias_s, const float* __restrict__ pi,
        const float* __restrict__ tl, const float* __restrict__ denom,
        float* __restrict__ out) {
    const int t = threadIdx.x;
    const int wave = t >> 6, lane = t & 63;
    const int g = lane >> 4, c = lane & 15;
    const int rbase = blockIdx.y * 64;
    const int brow0 = blockIdx.y * 16;
    __shared__ float s_cf[64];
    __shared__ float s_et[64];
    __shared__ float s_ls[4];
    __shared__ float s_stage[4*16*180];            // 46,080 B: wave-private tiles

    if (t < 64) {
        int row = rbase + t;
        float et = fexp2(tl[row]);
        float d  = denom[row] + et;
        s_cf[t] = pi[row] / d;
        s_et[t] = et;
    }
    __syncthreads();
    if (blockIdx.x == 0 && t < 16) {
        float p0 = 0.f;
        #pragma unroll
        for (int h = 0; h < 4; ++h) p0 += s_cf[t*4 + h] * s_et[t*4 + h];
        out[(size_t)(brow0 + t) * SP1] = p0;
    }
    if (blockIdx.x == 0 && blockIdx.y == 0) {
        float lg = 0.f;
        for (int b = t; b < BD; b += 256) {
            float p0 = 0.f;
            #pragma unroll
            for (int h = 0; h < 4; ++h) {
                float et = fexp2(tl[b*4 + h]);
                p0 += pi[b*4 + h] / (denom[b*4 + h] + et) * et;
            }
            lg += logf(p0);
        }
        #pragma unroll
        for (int m = 1; m < 64; m <<= 1) lg += __shfl_xor(lg, m);
        if (lane == 0) s_ls[wave] = lg;
        __syncthreads();
        if (t == 0)
            out[(size_t)BD * SP1] = -(s_ls[0]+s_ls[1]+s_ls[2]+s_ls[3]) * (1.f/(float)BD);
    }

    bf16x8 a0[4], a1[4];
    float cf[4][4];
    #pragma unroll
    for (int t4 = 0; t4 < 4; ++t4) {
        const bf16x8* ap = (const bf16x8*)(A + (size_t)(rbase + t4*16 + c)*64);
        a0[t4] = ap[g]; a1[t4] = ap[4 + g];
        #pragma unroll
        for (int r = 0; r < 4; ++r) cf[t4][r] = s_cf[t4*16 + g*4 + r];
    }

    float* swo = &s_stage[wave * 16*180];          // wave-private staging
    const int t0 = (blockIdx.x*4 + wave) * 44;
    bf16x8 b0A, b1A, b0B, b1B, b0C, b1C;
    float bbA, bbB, bbC;
    PPIPES(t0)
    PPIPES(t0 + 11)
    PPIPES(t0 + 22)
    PPIPES(t0 + 33)
}

extern "C" void kernel_launch(void* const* d_in, const int* in_sizes, int n_in,
                              void* d_out, int out_size, void* d_ws, size_t ws_size,
                              hipStream_t stream) {
    const float* inputs = (const float*)d_in[0];
    const float* emb    = (const float*)d_in[1];
    const float* proj   = (const float*)d_in[2];
    const float* mix    = (const float*)d_in[3];
    const float* biases = (const float*)d_in[4];
    const int*   label  = (const int*)d_in[5];
    const int*   sids   = (const int*)d_in[6];
    float* out = (float*)d_out;

    char* ws = (char*)d_ws;
    short* W      = (short*)(ws);                      // 2,883,584 B
    short* A      = (short*)(ws + 2883584);            // 524,288 B
    float* bias_s = (float*)(ws + 3407872);            // 90,112 B
    float* denom  = (float*)(ws + 3497984);            // 16,384 B
    float* pi     = (float*)(ws + 3514368);            // 16,384 B
    float* tl     = (float*)(ws + 3530752);            // 16,384 B

    k_setup<<<256, 256, 0, stream>>>(
        inputs, emb, proj, mix, biases, label, sids, A, pi, tl, W, bias_s, denom);
    k_denom<<<dim3(8, 64), 256, 0, stream>>>(A, W, bias_s, denom);
    k_probs<<<dim3(8, 64), 256, 0, stream>>>(A, W, bias_s, pi, tl, denom, out);
}

// Round 20
// 82.060 us; speedup vs baseline: 2.0879x; 1.0419x over previous
//
#include <hip/hip_runtime.h>

#define ED 64
#define HD 4
#define BD 1024
#define SNEG 22222
#define NT2 1408             // 8 col-groups x 176 tiles (4 waves x 44)
#define SPAD2 22528
#define SP1 (SNEG+1)         // 22223
#define LOGQ -3.81776242f
#define LOG2E 1.44269504f

typedef short bf16x8 __attribute__((ext_vector_type(8)));
typedef float f32x4 __attribute__((ext_vector_type(4)));

static __device__ __forceinline__ short f2bf(float f) {
    union { float f; unsigned u; } v; v.f = f;
    return (short)((v.u + 0x7FFFu + ((v.u >> 16) & 1u)) >> 16);
}

static __device__ __forceinline__ float fast_tanh(float x) {
    float ax = __builtin_fabsf(x);
    float e  = __expf(-2.f * ax);
    float t  = (1.f - e) / (1.f + e);
    return __builtin_copysignf(t, x);
}

static __device__ __forceinline__ float fexp2(float x) {
#if __has_builtin(__builtin_amdgcn_exp2f)
    return __builtin_amdgcn_exp2f(x);
#else
    return __expf(x * 0.69314718f);
#endif
}

// ---------------- kernel 1: fused setup, 256 blocks ------------------------
__global__ __launch_bounds__(256) void k_setup(
        const float* __restrict__ inputs, const float* __restrict__ emb,
        const float* __restrict__ proj,   const float* __restrict__ mix,
        const float* __restrict__ biases, const int* __restrict__ label,
        const int* __restrict__ sids,
        short* __restrict__ A, float* __restrict__ pi, float* __restrict__ tl,
        short* __restrict__ W, float* __restrict__ bias_s,
        float* __restrict__ denom) {
    const int blk = blockIdx.x, t = threadIdx.x;
    __shared__ float s_in[64];
    __shared__ float s_proj[256];
    __shared__ float s_mix[4];
    __shared__ float s_red[256];

    if (t < 16) denom[blk*16 + t] = 0.f;

    #pragma unroll 1
    for (int bi = 0; bi < 4; ++bi) {
        int b = blk*4 + bi;
        if (t < 64) s_in[t] = inputs[b*64 + t];
        __syncthreads();
        const float* pr = proj + t*64;
        float dot = 0.f;
        #pragma unroll
        for (int k = 0; k < 64; k += 4)
            dot += s_in[k]*pr[k] + s_in[k+1]*pr[k+1] + s_in[k+2]*pr[k+2] + s_in[k+3]*pr[k+3];
        float val = fast_tanh(dot);
        s_proj[t] = val;
        A[(b*4 + (t >> 6))*64 + (t & 63)] = f2bf(val * LOG2E);   // pre-scaled
        if (t < 4) {
            const float* mr = mix + t*64;
            float md = 0.f;
            for (int k = 0; k < 64; ++k) md += s_in[k]*mr[k];
            s_mix[t] = md;
        }
        int lab = label[b];
        s_red[t] = s_proj[t] * emb[(size_t)lab*64 + (t & 63)];
        __syncthreads();
        if (t < 4) {
            float m = fmaxf(fmaxf(s_mix[0], s_mix[1]), fmaxf(s_mix[2], s_mix[3]));
            float e0 = __expf(s_mix[0]-m), e1 = __expf(s_mix[1]-m);
            float e2 = __expf(s_mix[2]-m), e3 = __expf(s_mix[3]-m);
            pi[b*4 + t] = __expf(s_mix[t]-m) / (e0+e1+e2+e3);
            float sum = 0.f;
            for (int k = 0; k < 64; ++k) sum += s_red[t*64 + k];
            tl[b*4 + t] = (sum + biases[lab] - LOGQ) * LOG2E;    // base-2
        }
        __syncthreads();
    }

    #pragma unroll 1
    for (int rep = 0; rep < 3; ++rep) {
        int task = rep*256 + t;
        if (task >= 704) break;
        int s = blk*88 + (task >> 3);
        int l8 = task & 7;
        if (s < SNEG) {
            int id = sids[s];
            const float* src = emb + (size_t)id*64 + l8*8;
            bf16x8 o;
            #pragma unroll
            for (int j = 0; j < 8; ++j) o[j] = f2bf(src[j]);
            *(bf16x8*)(W + s*64 + l8*8) = o;
            if (l8 == 0) bias_s[s] = (biases[id] - LOGQ) * LOG2E;
        } else {
            bf16x8 o;
            #pragma unroll
            for (int j = 0; j < 8; ++j) o[j] = 0;
            *(bf16x8*)(W + s*64 + l8*8) = o;
            if (l8 == 0) bias_s[s] = -1e30f;
        }
    }
}

#define LOADT(S, T) { \
    const bf16x8* bp_ = (const bf16x8*)(W + (size_t)((T)*16 + c)*64); \
    b0##S = bp_[g]; b1##S = bp_[4 + g]; bb##S = bias_s[(T)*16 + c]; }

#define DCOMP(S) { \
    _Pragma("unroll") \
    for (int t4 = 0; t4 < 4; ++t4) { \
        f32x4 z = {bb##S, bb##S, bb##S, bb##S}; \
        z = __builtin_amdgcn_mfma_f32_16x16x32_bf16(a0[t4], b0##S, z, 0, 0, 0); \
        z = __builtin_amdgcn_mfma_f32_16x16x32_bf16(a1[t4], b1##S, z, 0, 0, 0); \
        s[t4*4+0] += fexp2(z[0]); \
        s[t4*4+1] += fexp2(z[1]); \
        s[t4*4+2] += fexp2(z[2]); \
        s[t4*4+3] += fexp2(z[3]); } }

#define PCOMP(S, T) { \
    int scol_ = (T)*16 + c; bool ok_ = scol_ < SNEG; \
    _Pragma("unroll") \
    for (int t4 = 0; t4 < 4; ++t4) { \
        f32x4 z = {bb##S, bb##S, bb##S, bb##S}; \
        z = __builtin_amdgcn_mfma_f32_16x16x32_bf16(a0[t4], b0##S, z, 0, 0, 0); \
        z = __builtin_amdgcn_mfma_f32_16x16x32_bf16(a1[t4], b1##S, z, 0, 0, 0); \
        float p_ = cf[t4][0]*fexp2(z[0]); \
        p_ = fmaf(cf[t4][1], fexp2(z[1]), p_); \
        p_ = fmaf(cf[t4][2], fexp2(z[2]), p_); \
        p_ = fmaf(cf[t4][3], fexp2(z[3]), p_); \
        if (ok_) orow[t4][scol_] = p_; } }

#define DPIPE(TB) { \
    LOADT(A, (TB)+0) LOADT(B, (TB)+1) LOADT(C, (TB)+2) \
    DCOMP(A) LOADT(A, (TB)+3) \
    DCOMP(B) LOADT(B, (TB)+4) \
    DCOMP(C) LOADT(C, (TB)+5) \
    DCOMP(A) LOADT(A, (TB)+6) \
    DCOMP(B) LOADT(B, (TB)+7) \
    DCOMP(C) LOADT(C, (TB)+8) \
    DCOMP(A) LOADT(A, (TB)+9) \
    DCOMP(B) LOADT(B, (TB)+10) \
    DCOMP(C) \
    DCOMP(A) \
    DCOMP(B) }

#define PPIPE(TB) { \
    LOADT(A, (TB)+0) LOADT(B, (TB)+1) LOADT(C, (TB)+2) \
    PCOMP(A, (TB)+0)  LOADT(A, (TB)+3) \
    PCOMP(B, (TB)+1)  LOADT(B, (TB)+4) \
    PCOMP(C, (TB)+2)  LOADT(C, (TB)+5) \
    PCOMP(A, (TB)+3)  LOADT(A, (TB)+6) \
    PCOMP(B, (TB)+4)  LOADT(B, (TB)+7) \
    PCOMP(C, (TB)+5)  LOADT(C, (TB)+8) \
    PCOMP(A, (TB)+6)  LOADT(A, (TB)+9) \
    PCOMP(B, (TB)+7)  LOADT(B, (TB)+10) \
    PCOMP(C, (TB)+8) \
    PCOMP(A, (TB)+9) \
    PCOMP(B, (TB)+10) }

// ---------------- kernel 2: denominators, 512 blocks (XCD-swizzled) --------
// 1D grid; bx = blk&7, by = blk>>3. Round-robin XCD = blk%8 = bx: all 64
// consumer blocks of W-slice bx land on XCD bx -> W slice L2-local per XCD.
__global__ __launch_bounds__(256, 4) void k_denom(
        const short* __restrict__ A, const short* __restrict__ W,
        const float* __restrict__ bias_s, float* __restrict__ denom) {
    const int wave = threadIdx.x >> 6, lane = threadIdx.x & 63;
    const int g = lane >> 4, c = lane & 15;
    const int bx = blockIdx.x & 7, by = blockIdx.x >> 3;
    const int rbase = by * 64;
    bf16x8 a0[4], a1[4];
    #pragma unroll
    for (int t4 = 0; t4 < 4; ++t4) {
        const bf16x8* ap = (const bf16x8*)(A + (size_t)(rbase + t4*16 + c)*64);
        a0[t4] = ap[g]; a1[t4] = ap[4 + g];
    }
    float s[16];
    #pragma unroll
    for (int i = 0; i < 16; ++i) s[i] = 0.f;

    const int t0 = (bx*4 + wave) * 44;
    bf16x8 b0A, b1A, b0B, b1B, b0C, b1C;
    float bbA, bbB, bbC;
    DPIPE(t0)
    DPIPE(t0 + 11)
    DPIPE(t0 + 22)
    DPIPE(t0 + 33)

    #pragma unroll
    for (int m = 1; m < 16; m <<= 1)
        #pragma unroll
        for (int i = 0; i < 16; ++i) s[i] += __shfl_xor(s[i], m);
    if (c == 0) {
        #pragma unroll
        for (int t4 = 0; t4 < 4; ++t4)
            #pragma unroll
            for (int r = 0; r < 4; ++r)
                atomicAdd(&denom[rbase + t4*16 + g*4 + r], s[t4*4+r]);
    }
}

// ---------------- kernel 3: probs + out[:,0] + loss, 512 blocks ------------
__global__ __launch_bounds__(256, 4) void k_probs(
        const short* __restrict__ A, const short* __restrict__ W,
        const float* __restrict__ bias_s, const float* __restrict__ pi,
        const float* __restrict__ tl, const float* __restrict__ denom,
        float* __restrict__ out) {
    const int t = threadIdx.x;
    const int wave = t >> 6, lane = t & 63;
    const int g = lane >> 4, c = lane & 15;
    const int bx = blockIdx.x & 7, by = blockIdx.x >> 3;
    const int rbase = by * 64;
    __shared__ float s_cf[64];
    __shared__ float s_et[64];
    __shared__ float s_ls[4];

    if (t < 64) {
        int row = rbase + t;
        float et = fexp2(tl[row]);
        float d  = denom[row] + et;
        s_cf[t] = pi[row] / d;
        s_et[t] = et;
    }
    __syncthreads();
    if (bx == 0 && t < 16) {
        float p0 = 0.f;
        #pragma unroll
        for (int h = 0; h < 4; ++h) p0 += s_cf[t*4 + h] * s_et[t*4 + h];
        out[(size_t)(rbase/4 + t) * SP1] = p0;
    }
    if (blockIdx.x == 0) {
        float lg = 0.f;
        for (int b = t; b < BD; b += 256) {
            float p0 = 0.f;
            #pragma unroll
            for (int h = 0; h < 4; ++h) {
                float et = fexp2(tl[b*4 + h]);
                p0 += pi[b*4 + h] / (denom[b*4 + h] + et) * et;
            }
            lg += logf(p0);
        }
        #pragma unroll
        for (int m = 1; m < 64; m <<= 1) lg += __shfl_xor(lg, m);
        if (lane == 0) s_ls[wave] = lg;
        __syncthreads();
        if (t == 0)
            out[(size_t)BD * SP1] = -(s_ls[0]+s_ls[1]+s_ls[2]+s_ls[3]) * (1.f/(float)BD);
    }

    bf16x8 a0[4], a1[4];
    float cf[4][4];
    float* orow[4];
    #pragma unroll
    for (int t4 = 0; t4 < 4; ++t4) {
        const bf16x8* ap = (const bf16x8*)(A + (size_t)(rbase + t4*16 + c)*64);
        a0[t4] = ap[g]; a1[t4] = ap[4 + g];
        #pragma unroll
        for (int r = 0; r < 4; ++r) cf[t4][r] = s_cf[t4*16 + g*4 + r];
        orow[t4] = out + (size_t)(rbase/4 + t4*4 + g) * SP1 + 1;
    }

    const int t0 = (bx*4 + wave) * 44;
    bf16x8 b0A, b1A, b0B, b1B, b0C, b1C;
    float bbA, bbB, bbC;
    PPIPE(t0)
    PPIPE(t0 + 11)
    PPIPE(t0 + 22)
    PPIPE(t0 + 33)
}

extern "C" void kernel_launch(void* const* d_in, const int* in_sizes, int n_in,
                              void* d_out, int out_size, void* d_ws, size_t ws_size,
                              hipStream_t stream) {
    const float* inputs = (const float*)d_in[0];
    const float* emb    = (const float*)d_in[1];
    const float* proj   = (const float*)d_in[2];
    const float* mix    = (const float*)d_in[3];
    const float* biases = (const float*)d_in[4];
    const int*   label  = (const int*)d_in[5];
    const int*   sids   = (const int*)d_in[6];
    float* out = (float*)d_out;

    char* ws = (char*)d_ws;
    short* W      = (short*)(ws);                      // 2,883,584 B
    short* A      = (short*)(ws + 2883584);            // 524,288 B
    float* bias_s = (float*)(ws + 3407872);            // 90,112 B
    float* denom  = (float*)(ws + 3497984);            // 16,384 B
    float* pi     = (float*)(ws + 3514368);            // 16,384 B
    float* tl     = (float*)(ws + 3530752);            // 16,384 B

    k_setup<<<256, 256, 0, stream>>>(
        inputs, emb, proj, mix, biases, label, sids, A, pi, tl, W, bias_s, denom);
    k_denom<<<512, 256, 0, stream>>>(A, W, bias_s, denom);
    k_probs<<<512, 256, 0, stream>>>(A, W, bias_s, pi, tl, denom, out);
}